// Round 15
// baseline (225.329 us; speedup 1.0000x reference)
//
#include <hip/hip_runtime.h>

typedef __attribute__((ext_vector_type(8))) short short8;
typedef __attribute__((ext_vector_type(4))) float f32x4;

#define DIM  1024
#define BT   8192   // B * TGT rows
#define NBAT 8
#define KSOFF (1 << 29)   // KSPLIT value meaning "disabled"

__device__ __forceinline__ unsigned short f2bf(float x){
  union { float f; unsigned u; } un; un.f = x;
  unsigned r = un.u + 0x7fffu + ((un.u >> 16) & 1u);   // round-to-nearest-even
  return (unsigned short)(r >> 16);
}
__device__ __forceinline__ float bf2f(unsigned short h){
  union { unsigned u; float f; } un; un.u = ((unsigned)h) << 16;
  return un.f;
}

// merged elementwise prep: input split + Win split + Wout cvt in ONE launch.
__global__ void prep_kernel(const float* __restrict__ in,
                            unsigned short* __restrict__ in_hi,
                            unsigned short* __restrict__ in_lo,
                            const float* __restrict__ Win,
                            unsigned short* __restrict__ wi_hi,
                            unsigned short* __restrict__ wi_lo,
                            const float* __restrict__ Wout,
                            unsigned short* __restrict__ wo_hi){
  const int N0 = (BT * DIM) >> 2;             // input float4s
  const int N1 = N0 + ((DIM * DIM) >> 2);     // + Win
  const int N2 = N1 + ((DIM * 2 * DIM) >> 2); // + Wout
  int stride = gridDim.x * blockDim.x;
  for (int i = blockIdx.x * blockDim.x + threadIdx.x; i < N2; i += stride){
    if (i < N0){
      float4 v = ((const float4*)in)[i];
      ushort4 h, l;
      h.x = f2bf(v.x); l.x = f2bf(v.x - bf2f(h.x));
      h.y = f2bf(v.y); l.y = f2bf(v.y - bf2f(h.y));
      h.z = f2bf(v.z); l.z = f2bf(v.z - bf2f(h.z));
      h.w = f2bf(v.w); l.w = f2bf(v.w - bf2f(h.w));
      ((ushort4*)in_hi)[i] = h;
      ((ushort4*)in_lo)[i] = l;
    } else if (i < N1){
      int j = i - N0;
      float4 v = ((const float4*)Win)[j];
      ushort4 h, l;
      h.x = f2bf(v.x); l.x = f2bf(v.x - bf2f(h.x));
      h.y = f2bf(v.y); l.y = f2bf(v.y - bf2f(h.y));
      h.z = f2bf(v.z); l.z = f2bf(v.z - bf2f(h.z));
      h.w = f2bf(v.w); l.w = f2bf(v.w - bf2f(h.w));
      ((ushort4*)wi_hi)[j] = h;
      ((ushort4*)wi_lo)[j] = l;
    } else {
      int j = i - N1;
      float4 v = ((const float4*)Wout)[j];
      ushort4 h;
      h.x = f2bf(v.x); h.y = f2bf(v.y); h.z = f2bf(v.z); h.w = f2bf(v.w);
      ((ushort4*)wo_hi)[j] = h;
    }
  }
}

// fused: context [b][s][d] f32 -> cx_hi/cx_lo [b][s][d] bf16 + ctxT [b][d][s]
// bf16 (hi).  Single read of context.
__global__ void ctx_prep_kernel(const float* __restrict__ ctx,
                                unsigned short* __restrict__ hi,
                                unsigned short* __restrict__ lo,
                                unsigned short* __restrict__ ctxT){
  __shared__ unsigned short t[64][65];
  int bz = blockIdx.z;
  int s0 = blockIdx.x << 6, d0 = blockIdx.y << 6;
  int tx = threadIdx.x, ty = threadIdx.y;   // (64,4)
  const size_t base = (((size_t)bz << 10) + s0) * DIM + d0;
  const float* src = ctx + base;
  unsigned short* hrow = hi + base;
  unsigned short* lrow = lo + base;
  #pragma unroll
  for (int i = ty; i < 64; i += 4){
    float v = src[(size_t)i * DIM + tx];
    unsigned short h = f2bf(v);
    hrow[(size_t)i * DIM + tx] = h;
    lrow[(size_t)i * DIM + tx] = f2bf(v - bf2f(h));
    t[i][tx] = h;
  }
  __syncthreads();
  unsigned short* dst = ctxT + (((size_t)bz << 10) + d0) * DIM + s0;
  #pragma unroll
  for (int i = ty; i < 64; i += 4)
    dst[(size_t)i * DIM + tx] = t[tx][i];
}

// masked softmax over rows of 1024; P f32 in place + P bf16 to Pb.
__global__ __launch_bounds__(256) void softmax_kernel(float* __restrict__ sc,
                                                      unsigned short* __restrict__ Pb,
                                                      const int* __restrict__ lens){
  const int row = blockIdx.x;
  const int len = lens[row >> 10];
  const int tid = threadIdx.x;
  const int lane = tid & 63, wid = tid >> 6;
  float* rp = sc + ((size_t)row << 10);
  const int s0 = tid << 2;
  float4 v;
  if (s0 < len) v = ((const float4*)rp)[tid];
  else          v = (float4){0.f, 0.f, 0.f, 0.f};
  float x0 = (s0 + 0 < len) ? v.x : -INFINITY;
  float x1 = (s0 + 1 < len) ? v.y : -INFINITY;
  float x2 = (s0 + 2 < len) ? v.z : -INFINITY;
  float x3 = (s0 + 3 < len) ? v.w : -INFINITY;
  float wmax = fmaxf(fmaxf(x0, x1), fmaxf(x2, x3));
  #pragma unroll
  for (int o = 32; o > 0; o >>= 1) wmax = fmaxf(wmax, __shfl_xor(wmax, o));
  __shared__ float red[8];
  if (lane == 0) red[wid] = wmax;
  __syncthreads();
  float mx = fmaxf(fmaxf(red[0], red[1]), fmaxf(red[2], red[3]));
  float e0 = (s0 + 0 < len) ? __expf(x0 - mx) : 0.f;
  float e1 = (s0 + 1 < len) ? __expf(x1 - mx) : 0.f;
  float e2 = (s0 + 2 < len) ? __expf(x2 - mx) : 0.f;
  float e3 = (s0 + 3 < len) ? __expf(x3 - mx) : 0.f;
  float ws = e0 + e1 + e2 + e3;
  #pragma unroll
  for (int o = 32; o > 0; o >>= 1) ws += __shfl_xor(ws, o);
  if (lane == 0) red[4 + wid] = ws;
  __syncthreads();
  float inv = 1.f / (red[4] + red[5] + red[6] + red[7]);
  float4 p; p.x = e0 * inv; p.y = e1 * inv; p.z = e2 * inv; p.w = e3 * inv;
  ((float4*)rp)[tid] = p;
  ushort4 pb; pb.x = f2bf(p.x); pb.y = f2bf(p.y); pb.z = f2bf(p.z); pb.w = f2bf(p.w);
  ((ushort4*)(Pb + ((size_t)row << 10)))[tid] = pb;
}

// LDS layout for a Rx32 bf16 tile: element (r,k) at byte
//   r*64 + ((k>>3) ^ ((r>>1)&3))*16 + (k&7)*2
__device__ __forceinline__ int lds_off(int r, int kb){
  return r * 64 + (((kb ^ ((r >> 1) & 3))) << 4);
}

__device__ __forceinline__ void gld16(void* lds, const void* g){
  __builtin_amdgcn_global_load_lds(
      (__attribute__((address_space(1))) void*)(g),
      (__attribute__((address_space(3))) void*)(lds), 16, 0, 0);
}

// ---------------------------------------------------------------------------
// 2-barrier 128x128 GEMM, 4 waves of 64x64, gld16 staging (rule 21).
// STRUCTURE RULE (R13): use for HIGH-INTENSITY steps (SPLIT: 48 MFMAs/step
// amortize the vmcnt(0) drain -> 886-930 TF measured).
// ---------------------------------------------------------------------------
template<bool SPLIT, int EPI, int KSPLIT>
__global__ __launch_bounds__(256, 2) void gemm_kernel(
    const unsigned short* __restrict__ Ah,  const unsigned short* __restrict__ Al,
    const unsigned short* __restrict__ Ah2, const unsigned short* __restrict__ Al2,
    const unsigned short* __restrict__ Bh,  const unsigned short* __restrict__ Bl,
    int K, int lda, int ldb,
    long long aStride, long long bStride, long long oStride,
    float* __restrict__ outF, unsigned short* __restrict__ o1,
    unsigned short* __restrict__ o2, int ldo,
    const int* __restrict__ lens, int lmode)
{
  constexpr int TILE = 128 * 64;  // bytes per staged tile
  __shared__ __align__(16) char smem[(SPLIT ? 4 : 2) * TILE];
  char* sAh = smem;
  char* sBh = smem + TILE;
  char* sAl = smem + (SPLIT ? 2 : 0) * TILE;
  char* sBl = smem + (SPLIT ? 3 : 0) * TILE;

  const int tid  = threadIdx.x;
  const int lane = tid & 63;
  const int wid  = tid >> 6;
  const int z    = blockIdx.z;

  int bx = blockIdx.x, by = blockIdx.y;
  if (gridDim.x == 8 && gridDim.y == 8){
    int o = bx + (by << 3);
    int k = o & 7, j = o >> 3;
    bx = ((k & 3) << 1) | (j & 1);  by = ((k >> 2) << 2) | (j >> 1);
  } else if (gridDim.x == 8 && (gridDim.y & 7) == 0){
    int o = bx + (by << 3);
    int xcd = o & 7, j = o >> 3;
    bx = j & 7;
    by = xcd * (gridDim.y >> 3) + (j >> 3);
  }
  const int m0 = by * 128;
  const int n0 = bx * 128;

  int Keff = K;
  if (lmode){
    const int len = lens[z];
    if (lmode == 1 && n0 >= len) return;       // output fully masked downstream
    if (lmode == 2){
      int kc = (len + 31) & ~31;
      Keff = kc < K ? kc : K;                  // P is exactly 0 beyond len
    }
  }

  const unsigned short* gAh  = Ah  + (size_t)z * aStride + (size_t)m0 * lda;
  const unsigned short* gAh2 = Ah2 + (size_t)z * aStride + (size_t)m0 * lda;
  const unsigned short* gBh  = Bh  + (size_t)z * bStride + (size_t)n0 * ldb;
  const unsigned short* gAl  = SPLIT ? (Al  + (size_t)z * aStride + (size_t)m0 * lda) : (const unsigned short*)0;
  const unsigned short* gAl2 = SPLIT ? (Al2 + (size_t)z * aStride + (size_t)m0 * lda) : (const unsigned short*)0;
  const unsigned short* gBl  = SPLIT ? (Bl  + (size_t)z * bStride + (size_t)n0 * ldb) : (const unsigned short*)0;

  const int rS0 = (wid << 5) + (lane >> 2);
  const int rS1 = rS0 + 16;
  const int cS0 = ((lane & 3) ^ ((rS0 >> 1) & 3)) << 3;
  const int cS1 = ((lane & 3) ^ ((rS1 >> 1) & 3)) << 3;
  const int dS0 = (wid << 5) << 6;
  const int dS1 = dS0 + (16 << 6);
  const unsigned short* qAh0  = gAh  + (size_t)rS0 * lda + cS0;
  const unsigned short* qAh1  = gAh  + (size_t)rS1 * lda + cS1;
  const unsigned short* qAh20 = gAh2 + (size_t)rS0 * lda + cS0;
  const unsigned short* qAh21 = gAh2 + (size_t)rS1 * lda + cS1;
  const unsigned short* qBh0  = gBh  + (size_t)rS0 * ldb + cS0;
  const unsigned short* qBh1  = gBh  + (size_t)rS1 * ldb + cS1;
  const unsigned short* qAl0  = SPLIT ? (gAl  + (size_t)rS0 * lda + cS0) : (const unsigned short*)0;
  const unsigned short* qAl1  = SPLIT ? (gAl  + (size_t)rS1 * lda + cS1) : (const unsigned short*)0;
  const unsigned short* qAl20 = SPLIT ? (gAl2 + (size_t)rS0 * lda + cS0) : (const unsigned short*)0;
  const unsigned short* qAl21 = SPLIT ? (gAl2 + (size_t)rS1 * lda + cS1) : (const unsigned short*)0;
  const unsigned short* qBl0  = SPLIT ? (gBl  + (size_t)rS0 * ldb + cS0) : (const unsigned short*)0;
  const unsigned short* qBl1  = SPLIT ? (gBl  + (size_t)rS1 * ldb + cS1) : (const unsigned short*)0;

  f32x4 acc[4][4];
  #pragma unroll
  for (int m = 0; m < 4; m++)
    #pragma unroll
    for (int n = 0; n < 4; n++)
      acc[m][n] = (f32x4){0.f, 0.f, 0.f, 0.f};

  const int wr = (wid >> 1) * 64;
  const int wc = (wid & 1) * 64;
  const int fr = lane & 15;
  const int kb = lane >> 4;

  for (int k0 = 0; k0 < Keff; k0 += 32){
    __syncthreads();                      // WAR: all reads of prev tile done
    const unsigned short *a0, *a1, *l0 = 0, *l1 = 0;
    if (KSPLIT != KSOFF && k0 >= KSPLIT){
      int q = k0 - KSPLIT;
      a0 = qAh20 + q; a1 = qAh21 + q;
      if (SPLIT){ l0 = qAl20 + q; l1 = qAl21 + q; }
    } else {
      a0 = qAh0 + k0; a1 = qAh1 + k0;
      if (SPLIT){ l0 = qAl0 + k0; l1 = qAl1 + k0; }
    }
    gld16(sAh + dS0, a0);
    gld16(sAh + dS1, a1);
    gld16(sBh + dS0, qBh0 + k0);
    gld16(sBh + dS1, qBh1 + k0);
    if (SPLIT){
      gld16(sAl + dS0, l0);
      gld16(sAl + dS1, l1);
      gld16(sBl + dS0, qBl0 + k0);
      gld16(sBl + dS1, qBl1 + k0);
    }
    __syncthreads();                      // drains vmcnt -> tile visible

    short8 ah[4], bh[4], al[4], bl[4];
    #pragma unroll
    for (int m = 0; m < 4; m++){
      int off = lds_off(wr + m * 16 + fr, kb);
      ah[m] = *(const short8*)(sAh + off);
      if (SPLIT) al[m] = *(const short8*)(sAl + off);
    }
    #pragma unroll
    for (int n = 0; n < 4; n++){
      int off = lds_off(wc + n * 16 + fr, kb);
      bh[n] = *(const short8*)(sBh + off);
      if (SPLIT) bl[n] = *(const short8*)(sBl + off);
    }
    #pragma unroll
    for (int m = 0; m < 4; m++)
      #pragma unroll
      for (int n = 0; n < 4; n++){
        acc[m][n] = __builtin_amdgcn_mfma_f32_16x16x32_bf16(ah[m], bh[n], acc[m][n], 0, 0, 0);
        if (SPLIT){
          acc[m][n] = __builtin_amdgcn_mfma_f32_16x16x32_bf16(ah[m], bl[n], acc[m][n], 0, 0, 0);
          acc[m][n] = __builtin_amdgcn_mfma_f32_16x16x32_bf16(al[m], bh[n], acc[m][n], 0, 0, 0);
        }
      }
  }

  // epilogue: C/D layout col = lane&15, row = (lane>>4)*4 + reg  [m89-verified]
  const int rbase = (lane >> 4) * 2 * 2;
  const int cbase = lane & 15;
  #pragma unroll
  for (int m = 0; m < 4; m++){
    #pragma unroll
    for (int n = 0; n < 4; n++){
      f32x4 v = acc[m][n];
      int col = n0 + wc + n * 16 + cbase;
      #pragma unroll
      for (int j = 0; j < 4; j++){
        int row = m0 + wr + m * 16 + rbase + j;
        float val = v[j];
        size_t idx = (size_t)row * ldo + col;
        if (EPI == 0){
          unsigned short h = f2bf(val);
          o1[(size_t)z * oStride + idx] = h;
          o2[(size_t)z * oStride + idx] = f2bf(val - bf2f(h));
        } else if (EPI == 1){
          outF[(size_t)z * oStride + idx] = val;
        } else if (EPI == 4){
          o1[(size_t)z * oStride + idx] = f2bf(val);
        } else {
          outF[idx] = tanhf(val);
        }
      }
    }
  }
}

// ---------------------------------------------------------------------------
// GEMM4 kernel: BK=64 DOUBLE-BUFFERED 128x128, 4 waves of 64x64, pure bf16,
// A split at KSPLIT ([c | input]).  Two 32KB buffers (64KB -> 2 blocks/CU).
// Per step: stage tile t+1 (8 gld16) at top, straight-line compute of tile t
// (16 ds_reads + 32 MFMAs, NO intra-step barriers -- buffers disjoint, lgkm
// waits compiler-scheduled), then vmcnt(0)+one barrier.  Barriers drop from
// 8-per-16-MFMAs (R12 pipe, 732 TF) to 1-per-32; wait window = full step.
// Accumulation order per acc unchanged (k ascending 32-chunks) -> bits same.
// ---------------------------------------------------------------------------
template<int EPI, int NT, int KSPLIT>   // NT = K/64
__global__ __launch_bounds__(256, 2) void gemm_dbuf64_kernel(
    const unsigned short* __restrict__ Ah, const unsigned short* __restrict__ Ah2,
    const unsigned short* __restrict__ Bh,
    int lda, int ldb,
    float* __restrict__ outF, unsigned short* __restrict__ o1, int ldo)
{
  constexpr int SUB   = 8192;             // one 128x32 sub-tile (bytes)
  constexpr int OFF_B = 2 * SUB;          // A halves at 0,SUB; B at 2SUB,3SUB
  constexpr int BUF   = 4 * SUB;          // 32 KB

  __shared__ __align__(16) char sm0[BUF];
  __shared__ __align__(16) char sm1[BUF];

  const int tid  = threadIdx.x;
  const int lane = tid & 63;
  const int w    = tid >> 6;              // 0..3

  int bx = blockIdx.x, by = blockIdx.y;
  { // XCD swizzle (grid (8,64))
    int o = bx + (by << 3);
    int xcd = o & 7, j = o >> 3;
    bx = j & 7;
    by = xcd * (gridDim.y >> 3) + (j >> 3);
  }
  const int m0 = by << 7;
  const int n0 = bx << 7;

  const unsigned short* gAh  = Ah  + (size_t)m0 * lda;
  const unsigned short* gAh2 = Ah2 + (size_t)m0 * lda;
  const unsigned short* gBh  = Bh  + (size_t)n0 * ldb;

  // staging plan (per 128x32 sub-tile): wave w covers rows 32w..32w+31,
  // 2 gld16; lane l -> row rS+(l>>2), physical chunk (l&3), global source
  // chunk (l&3)^((r>>1)&3)  (pre-swizzled source, linear dest -- rule 21).
  const int rS0 = (w << 5) + (lane >> 2);
  const int rS1 = rS0 + 16;
  const int cS0 = ((lane & 3) ^ ((rS0 >> 1) & 3)) << 3;
  const int cS1 = ((lane & 3) ^ ((rS1 >> 1) & 3)) << 3;
  const unsigned short* pA0  = gAh  + (size_t)rS0 * lda + cS0;
  const unsigned short* pA1  = gAh  + (size_t)rS1 * lda + cS1;
  const unsigned short* pA20 = gAh2 + (size_t)rS0 * lda + cS0;
  const unsigned short* pA21 = gAh2 + (size_t)rS1 * lda + cS1;
  const unsigned short* pB0  = gBh  + (size_t)rS0 * ldb + cS0;
  const unsigned short* pB1  = gBh  + (size_t)rS1 * ldb + cS1;
  const int dS0 = (w << 5) << 6;
  const int dS1 = dS0 + (16 << 6);

  f32x4 acc[4][4];
  #pragma unroll
  for (int m = 0; m < 4; m++)
    #pragma unroll
    for (int n = 0; n < 4; n++)
      acc[m][n] = (f32x4){0.f, 0.f, 0.f, 0.f};

  const int wr = (w >> 1) << 6;
  const int wc = (w & 1) << 6;
  const int fr = lane & 15;
  const int kb = lane >> 4;

// stage one 32-wide k-chunk (k elems) into sub-tile H of buffer WR
#define STAGE_H(WR, H, KE) do { int _k = (KE);                              \
    const unsigned short *_s0, *_s1;                                        \
    if (_k >= KSPLIT){ int _q = _k - KSPLIT; _s0 = pA20 + _q; _s1 = pA21 + _q; } \
    else             { _s0 = pA0 + _k;       _s1 = pA1 + _k; }              \
    gld16(WR + (H) * SUB + dS0, _s0);                                       \
    gld16(WR + (H) * SUB + dS1, _s1);                                       \
    gld16(WR + OFF_B + (H) * SUB + dS0, pB0 + _k);                          \
    gld16(WR + OFF_B + (H) * SUB + dS1, pB1 + _k);                          \
  } while(0)

#define STAGE64(WR, T1) do {                                                \
    STAGE_H(WR, 0, (T1) * 64);                                              \
    STAGE_H(WR, 1, (T1) * 64 + 32);                                         \
  } while(0)

// compute one 32-wide k-chunk from sub-tile H of buffer RD (no barriers)
#define HALF(RD, H) do {                                                    \
    short8 bh[4], ah;                                                       \
    _Pragma("unroll")                                                       \
    for (int n = 0; n < 4; n++)                                             \
      bh[n] = *(const short8*)((RD) + OFF_B + (H) * SUB + lds_off(wc + n * 16 + fr, kb)); \
    _Pragma("unroll")                                                       \
    for (int m = 0; m < 4; m++){                                            \
      ah = *(const short8*)((RD) + (H) * SUB + lds_off(wr + m * 16 + fr, kb)); \
      __builtin_amdgcn_s_setprio(1);                                        \
      _Pragma("unroll")                                                     \
      for (int n = 0; n < 4; n++)                                           \
        acc[m][n] = __builtin_amdgcn_mfma_f32_16x16x32_bf16(ah, bh[n], acc[m][n], 0, 0, 0); \
      __builtin_amdgcn_s_setprio(0);                                        \
    }                                                                       \
  } while(0)

#define BAR() do { __builtin_amdgcn_s_barrier();                            \
                   asm volatile("" ::: "memory"); } while(0)

#define STEP64(RD, WR, T) do {                                              \
    if ((T) + 1 < NT) STAGE64(WR, (T) + 1);                                 \
    HALF(RD, 0);                                                            \
    HALF(RD, 1);                                                            \
    asm volatile("s_waitcnt vmcnt(0)" ::: "memory");                        \
    BAR();                                                                  \
  } while(0)

  STAGE64(sm0, 0);
  asm volatile("s_waitcnt vmcnt(0)" ::: "memory");
  BAR();

  for (int t = 0; t < NT; t += 2){   // NT even (K=2048 -> NT=32)
    STEP64(sm0, sm1, t);
    STEP64(sm1, sm0, t + 1);
  }
#undef STAGE_H
#undef STAGE64
#undef HALF
#undef BAR
#undef STEP64

  // epilogue: C/D layout col = lane&15, row = (lane>>4)*4 + reg  [m89-verified]
  const int rbase = (lane >> 4) << 2;
  const int cbase = lane & 15;
  #pragma unroll
  for (int m = 0; m < 4; m++){
    #pragma unroll
    for (int n = 0; n < 4; n++){
      f32x4 v = acc[m][n];
      int col = n0 + wc + n * 16 + cbase;
      #pragma unroll
      for (int j = 0; j < 4; j++){
        int row = m0 + wr + m * 16 + rbase + j;
        float val = v[j];
        size_t idx = (size_t)row * ldo + col;
        if (EPI == 3) outF[idx] = tanhf(val);
        else          o1[idx] = f2bf(val);
      }
    }
  }
}

extern "C" void kernel_launch(void* const* d_in, const int* in_sizes, int n_in,
                              void* d_out, int out_size, void* d_ws, size_t ws_size,
                              hipStream_t stream){
  const float* input   = (const float*)d_in[0];
  const float* context = (const float*)d_in[1];
  const int*   lens    = (const int*)d_in[2];
  const float* Win     = (const float*)d_in[3];
  const float* Wout    = (const float*)d_in[4];
  float* attn  = (float*)d_out;
  float* align = attn + (size_t)BT * DIM;

  char* ws = (char*)d_ws;
  size_t off = 0;
  auto alloc = [&](size_t bytes) -> char* {
    char* p = ws + off; off += (bytes + 255) & ~(size_t)255; return p;
  };
  const size_t MTD = (size_t)BT * DIM;   // 8M elements
  unsigned short* in_hi = (unsigned short*)alloc(MTD * 2);
  unsigned short* in_lo = (unsigned short*)alloc(MTD * 2);
  unsigned short* cx_hi = (unsigned short*)alloc(MTD * 2);
  unsigned short* cx_lo = (unsigned short*)alloc(MTD * 2);
  unsigned short* wi_hi = (unsigned short*)alloc((size_t)DIM * DIM * 2);
  unsigned short* wi_lo = (unsigned short*)alloc((size_t)DIM * DIM * 2);
  unsigned short* ht_hi = (unsigned short*)alloc(MTD * 2);
  unsigned short* ht_lo = (unsigned short*)alloc(MTD * 2);
  unsigned short* cxT   = (unsigned short*)alloc(MTD * 2);
  unsigned short* c_hi  = (unsigned short*)alloc(MTD * 2);   // GEMM3 out (plain bf16)
  unsigned short* wo_hi = (unsigned short*)alloc((size_t)DIM * 2 * DIM * 2);
  unsigned short* p_bf  = cx_hi;   // alias: cx_hi dead after GEMM2
  if (off > ws_size) return;

  // prep: merged elementwise + fused context split/transpose
  prep_kernel<<<4096, 256, 0, stream>>>(input, in_hi, in_lo,
                                        Win, wi_hi, wi_lo, Wout, wo_hi);
  ctx_prep_kernel<<<dim3(16, 16, NBAT), dim3(64, 4), 0, stream>>>(context, cx_hi, cx_lo, cxT);

  // GEMM1: ht = input @ Win^T  (2-barrier 128^2 SPLIT, 930 TF measured R14)
  gemm_kernel<true, 0, KSOFF><<<dim3(8, 64, 1), 256, 0, stream>>>(
      in_hi, in_lo, in_hi, in_lo, wi_hi, wi_lo, DIM, DIM, DIM,
      0, 0, 0,
      nullptr, ht_hi, ht_lo, DIM, nullptr, 0);
  // GEMM2: scores[b] = ht[b] @ ctx[b]^T  (SPLIT, f32 out -> align; len-skip)
  gemm_kernel<true, 1, KSOFF><<<dim3(8, 8, NBAT), 256, 0, stream>>>(
      ht_hi, ht_lo, ht_hi, ht_lo, cx_hi, cx_lo, DIM, DIM, DIM,
      (long long)DIM * 1024, (long long)DIM * 1024, (long long)DIM * 1024,
      align, nullptr, nullptr, DIM, lens, 1);
  // masked softmax (in-place on align) + P bf16
  softmax_kernel<<<BT, 256, 0, stream>>>(align, p_bf, lens);
  // GEMM3: c[b] = P[b] @ ctxT[b]^T  (plain bf16, len-clamped K)
  gemm_kernel<false, 4, KSOFF><<<dim3(8, 8, NBAT), 256, 0, stream>>>(
      p_bf, nullptr, p_bf, nullptr, cxT, nullptr, DIM, DIM, DIM,
      (long long)DIM * 1024, (long long)DIM * 1024, (long long)1024 * 1024,
      nullptr, c_hi, nullptr, DIM, lens, 2);
  // GEMM4: attn = tanh([c | input] @ Wout^T)  (BK=64 double-buffered,
  //        1 barrier per 32 MFMAs, 2 blocks/CU)
  gemm_dbuf64_kernel<3, 32, 1024><<<dim3(8, 64), 256, 0, stream>>>(
      c_hi, in_hi, wo_hi, DIM, 2 * DIM,
      attn, nullptr, DIM);
}

// Round 16
// 223.072 us; speedup vs baseline: 1.0101x; 1.0101x over previous
//
#include <hip/hip_runtime.h>

typedef __attribute__((ext_vector_type(8))) short short8;
typedef __attribute__((ext_vector_type(4))) float f32x4;

#define DIM  1024
#define BT   8192   // B * TGT rows
#define NBAT 8
#define KSOFF (1 << 29)   // KSPLIT value meaning "disabled"

__device__ __forceinline__ unsigned short f2bf(float x){
  union { float f; unsigned u; } un; un.f = x;
  unsigned r = un.u + 0x7fffu + ((un.u >> 16) & 1u);   // round-to-nearest-even
  return (unsigned short)(r >> 16);
}
__device__ __forceinline__ float bf2f(unsigned short h){
  union { unsigned u; float f; } un; un.u = ((unsigned)h) << 16;
  return un.f;
}

// merged elementwise prep: input split + Win split + Wout cvt in ONE launch.
__global__ void prep_kernel(const float* __restrict__ in,
                            unsigned short* __restrict__ in_hi,
                            unsigned short* __restrict__ in_lo,
                            const float* __restrict__ Win,
                            unsigned short* __restrict__ wi_hi,
                            unsigned short* __restrict__ wi_lo,
                            const float* __restrict__ Wout,
                            unsigned short* __restrict__ wo_hi){
  const int N0 = (BT * DIM) >> 2;             // input float4s
  const int N1 = N0 + ((DIM * DIM) >> 2);     // + Win
  const int N2 = N1 + ((DIM * 2 * DIM) >> 2); // + Wout
  int stride = gridDim.x * blockDim.x;
  for (int i = blockIdx.x * blockDim.x + threadIdx.x; i < N2; i += stride){
    if (i < N0){
      float4 v = ((const float4*)in)[i];
      ushort4 h, l;
      h.x = f2bf(v.x); l.x = f2bf(v.x - bf2f(h.x));
      h.y = f2bf(v.y); l.y = f2bf(v.y - bf2f(h.y));
      h.z = f2bf(v.z); l.z = f2bf(v.z - bf2f(h.z));
      h.w = f2bf(v.w); l.w = f2bf(v.w - bf2f(h.w));
      ((ushort4*)in_hi)[i] = h;
      ((ushort4*)in_lo)[i] = l;
    } else if (i < N1){
      int j = i - N0;
      float4 v = ((const float4*)Win)[j];
      ushort4 h, l;
      h.x = f2bf(v.x); l.x = f2bf(v.x - bf2f(h.x));
      h.y = f2bf(v.y); l.y = f2bf(v.y - bf2f(h.y));
      h.z = f2bf(v.z); l.z = f2bf(v.z - bf2f(h.z));
      h.w = f2bf(v.w); l.w = f2bf(v.w - bf2f(h.w));
      ((ushort4*)wi_hi)[j] = h;
      ((ushort4*)wi_lo)[j] = l;
    } else {
      int j = i - N1;
      float4 v = ((const float4*)Wout)[j];
      ushort4 h;
      h.x = f2bf(v.x); h.y = f2bf(v.y); h.z = f2bf(v.z); h.w = f2bf(v.w);
      ((ushort4*)wo_hi)[j] = h;
    }
  }
}

// fused ctx prep, FULLY VECTORIZED (G13): context [b][s][d] f32 ->
// cx_hi/cx_lo bf16 + ctxT [b][d][s] bf16.  float4 loads (16B/lane),
// ushort4 stores everywhere incl. the transposed write (was 4B-load/
// 2B-store scalar).  Per-element math identical -> outputs bit-identical.
__global__ __launch_bounds__(256) void ctx_prep_kernel(
    const float* __restrict__ ctx,
    unsigned short* __restrict__ hi,
    unsigned short* __restrict__ lo,
    unsigned short* __restrict__ ctxT){
  __shared__ unsigned short t[64][65];
  const int bz = blockIdx.z;
  const int s0 = blockIdx.x << 6, d0 = blockIdx.y << 6;
  const int tid = threadIdx.x;        // 256
  const int rr = tid >> 4;            // 0..15
  const int cc = (tid & 15) << 2;     // 0,4,...,60
  const size_t base = (((size_t)bz << 10) + s0) * DIM + d0;
  #pragma unroll
  for (int p = 0; p < 4; p++){
    int r = p * 16 + rr;              // s-row within tile
    float4 v = *(const float4*)(ctx + base + (size_t)r * DIM + cc);
    ushort4 h, l;
    h.x = f2bf(v.x); l.x = f2bf(v.x - bf2f(h.x));
    h.y = f2bf(v.y); l.y = f2bf(v.y - bf2f(h.y));
    h.z = f2bf(v.z); l.z = f2bf(v.z - bf2f(h.z));
    h.w = f2bf(v.w); l.w = f2bf(v.w - bf2f(h.w));
    *(ushort4*)(hi + base + (size_t)r * DIM + cc) = h;
    *(ushort4*)(lo + base + (size_t)r * DIM + cc) = l;
    t[r][cc + 0] = h.x; t[r][cc + 1] = h.y;
    t[r][cc + 2] = h.z; t[r][cc + 3] = h.w;
  }
  __syncthreads();
  unsigned short* dst = ctxT + (((size_t)bz << 10) + d0) * DIM + s0;
  #pragma unroll
  for (int p = 0; p < 4; p++){
    int dr = p * 16 + rr;             // d-row within tile
    ushort4 o;
    o.x = t[cc + 0][dr]; o.y = t[cc + 1][dr];
    o.z = t[cc + 2][dr]; o.w = t[cc + 3][dr];
    *(ushort4*)(dst + (size_t)dr * DIM + cc) = o;
  }
}

// masked softmax over rows of 1024; P f32 in place + P bf16 to Pb.
__global__ __launch_bounds__(256) void softmax_kernel(float* __restrict__ sc,
                                                      unsigned short* __restrict__ Pb,
                                                      const int* __restrict__ lens){
  const int row = blockIdx.x;
  const int len = lens[row >> 10];
  const int tid = threadIdx.x;
  const int lane = tid & 63, wid = tid >> 6;
  float* rp = sc + ((size_t)row << 10);
  const int s0 = tid << 2;
  float4 v;
  if (s0 < len) v = ((const float4*)rp)[tid];
  else          v = (float4){0.f, 0.f, 0.f, 0.f};
  float x0 = (s0 + 0 < len) ? v.x : -INFINITY;
  float x1 = (s0 + 1 < len) ? v.y : -INFINITY;
  float x2 = (s0 + 2 < len) ? v.z : -INFINITY;
  float x3 = (s0 + 3 < len) ? v.w : -INFINITY;
  float wmax = fmaxf(fmaxf(x0, x1), fmaxf(x2, x3));
  #pragma unroll
  for (int o = 32; o > 0; o >>= 1) wmax = fmaxf(wmax, __shfl_xor(wmax, o));
  __shared__ float red[8];
  if (lane == 0) red[wid] = wmax;
  __syncthreads();
  float mx = fmaxf(fmaxf(red[0], red[1]), fmaxf(red[2], red[3]));
  float e0 = (s0 + 0 < len) ? __expf(x0 - mx) : 0.f;
  float e1 = (s0 + 1 < len) ? __expf(x1 - mx) : 0.f;
  float e2 = (s0 + 2 < len) ? __expf(x2 - mx) : 0.f;
  float e3 = (s0 + 3 < len) ? __expf(x3 - mx) : 0.f;
  float ws = e0 + e1 + e2 + e3;
  #pragma unroll
  for (int o = 32; o > 0; o >>= 1) ws += __shfl_xor(ws, o);
  if (lane == 0) red[4 + wid] = ws;
  __syncthreads();
  float inv = 1.f / (red[4] + red[5] + red[6] + red[7]);
  float4 p; p.x = e0 * inv; p.y = e1 * inv; p.z = e2 * inv; p.w = e3 * inv;
  ((float4*)rp)[tid] = p;
  ushort4 pb; pb.x = f2bf(p.x); pb.y = f2bf(p.y); pb.z = f2bf(p.z); pb.w = f2bf(p.w);
  ((ushort4*)(Pb + ((size_t)row << 10)))[tid] = pb;
}

// LDS layout for a Rx32 bf16 tile: element (r,k) at byte
//   r*64 + ((k>>3) ^ ((r>>1)&3))*16 + (k&7)*2
__device__ __forceinline__ int lds_off(int r, int kb){
  return r * 64 + (((kb ^ ((r >> 1) & 3))) << 4);
}

__device__ __forceinline__ void gld16(void* lds, const void* g){
  __builtin_amdgcn_global_load_lds(
      (__attribute__((address_space(1))) void*)(g),
      (__attribute__((address_space(3))) void*)(lds), 16, 0, 0);
}

// ---------------------------------------------------------------------------
// 2-barrier 128x128 GEMM, 4 waves of 64x64, gld16 staging (rule 21).
// STRUCTURE RULE (R13): use for HIGH-INTENSITY steps (SPLIT: 48 MFMAs/step
// amortize the vmcnt(0) drain -> 886-930 TF measured).
// ---------------------------------------------------------------------------
template<bool SPLIT, int EPI, int KSPLIT>
__global__ __launch_bounds__(256, 2) void gemm_kernel(
    const unsigned short* __restrict__ Ah,  const unsigned short* __restrict__ Al,
    const unsigned short* __restrict__ Ah2, const unsigned short* __restrict__ Al2,
    const unsigned short* __restrict__ Bh,  const unsigned short* __restrict__ Bl,
    int K, int lda, int ldb,
    long long aStride, long long bStride, long long oStride,
    float* __restrict__ outF, unsigned short* __restrict__ o1,
    unsigned short* __restrict__ o2, int ldo,
    const int* __restrict__ lens, int lmode)
{
  constexpr int TILE = 128 * 64;  // bytes per staged tile
  __shared__ __align__(16) char smem[(SPLIT ? 4 : 2) * TILE];
  char* sAh = smem;
  char* sBh = smem + TILE;
  char* sAl = smem + (SPLIT ? 2 : 0) * TILE;
  char* sBl = smem + (SPLIT ? 3 : 0) * TILE;

  const int tid  = threadIdx.x;
  const int lane = tid & 63;
  const int wid  = tid >> 6;
  const int z    = blockIdx.z;

  int bx = blockIdx.x, by = blockIdx.y;
  if (gridDim.x == 8 && gridDim.y == 8){
    int o = bx + (by << 3);
    int k = o & 7, j = o >> 3;
    bx = ((k & 3) << 1) | (j & 1);  by = ((k >> 2) << 2) | (j >> 1);
  } else if (gridDim.x == 8 && (gridDim.y & 7) == 0){
    int o = bx + (by << 3);
    int xcd = o & 7, j = o >> 3;
    bx = j & 7;
    by = xcd * (gridDim.y >> 3) + (j >> 3);
  }
  const int m0 = by * 128;
  const int n0 = bx * 128;

  int Keff = K;
  if (lmode){
    const int len = lens[z];
    if (lmode == 1 && n0 >= len) return;       // output fully masked downstream
    if (lmode == 2){
      int kc = (len + 31) & ~31;
      Keff = kc < K ? kc : K;                  // P is exactly 0 beyond len
    }
  }

  const unsigned short* gAh  = Ah  + (size_t)z * aStride + (size_t)m0 * lda;
  const unsigned short* gAh2 = Ah2 + (size_t)z * aStride + (size_t)m0 * lda;
  const unsigned short* gBh  = Bh  + (size_t)z * bStride + (size_t)n0 * ldb;
  const unsigned short* gAl  = SPLIT ? (Al  + (size_t)z * aStride + (size_t)m0 * lda) : (const unsigned short*)0;
  const unsigned short* gAl2 = SPLIT ? (Al2 + (size_t)z * aStride + (size_t)m0 * lda) : (const unsigned short*)0;
  const unsigned short* gBl  = SPLIT ? (Bl  + (size_t)z * bStride + (size_t)n0 * ldb) : (const unsigned short*)0;

  const int rS0 = (wid << 5) + (lane >> 2);
  const int rS1 = rS0 + 16;
  const int cS0 = ((lane & 3) ^ ((rS0 >> 1) & 3)) << 3;
  const int cS1 = ((lane & 3) ^ ((rS1 >> 1) & 3)) << 3;
  const int dS0 = (wid << 5) << 6;
  const int dS1 = dS0 + (16 << 6);
  const unsigned short* qAh0  = gAh  + (size_t)rS0 * lda + cS0;
  const unsigned short* qAh1  = gAh  + (size_t)rS1 * lda + cS1;
  const unsigned short* qAh20 = gAh2 + (size_t)rS0 * lda + cS0;
  const unsigned short* qAh21 = gAh2 + (size_t)rS1 * lda + cS1;
  const unsigned short* qBh0  = gBh  + (size_t)rS0 * ldb + cS0;
  const unsigned short* qBh1  = gBh  + (size_t)rS1 * ldb + cS1;
  const unsigned short* qAl0  = SPLIT ? (gAl  + (size_t)rS0 * lda + cS0) : (const unsigned short*)0;
  const unsigned short* qAl1  = SPLIT ? (gAl  + (size_t)rS1 * lda + cS1) : (const unsigned short*)0;
  const unsigned short* qAl20 = SPLIT ? (gAl2 + (size_t)rS0 * lda + cS0) : (const unsigned short*)0;
  const unsigned short* qAl21 = SPLIT ? (gAl2 + (size_t)rS1 * lda + cS1) : (const unsigned short*)0;
  const unsigned short* qBl0  = SPLIT ? (gBl  + (size_t)rS0 * ldb + cS0) : (const unsigned short*)0;
  const unsigned short* qBl1  = SPLIT ? (gBl  + (size_t)rS1 * ldb + cS1) : (const unsigned short*)0;

  f32x4 acc[4][4];
  #pragma unroll
  for (int m = 0; m < 4; m++)
    #pragma unroll
    for (int n = 0; n < 4; n++)
      acc[m][n] = (f32x4){0.f, 0.f, 0.f, 0.f};

  const int wr = (wid >> 1) * 64;
  const int wc = (wid & 1) * 64;
  const int fr = lane & 15;
  const int kb = lane >> 4;

  for (int k0 = 0; k0 < Keff; k0 += 32){
    __syncthreads();                      // WAR: all reads of prev tile done
    const unsigned short *a0, *a1, *l0 = 0, *l1 = 0;
    if (KSPLIT != KSOFF && k0 >= KSPLIT){
      int q = k0 - KSPLIT;
      a0 = qAh20 + q; a1 = qAh21 + q;
      if (SPLIT){ l0 = qAl20 + q; l1 = qAl21 + q; }
    } else {
      a0 = qAh0 + k0; a1 = qAh1 + k0;
      if (SPLIT){ l0 = qAl0 + k0; l1 = qAl1 + k0; }
    }
    gld16(sAh + dS0, a0);
    gld16(sAh + dS1, a1);
    gld16(sBh + dS0, qBh0 + k0);
    gld16(sBh + dS1, qBh1 + k0);
    if (SPLIT){
      gld16(sAl + dS0, l0);
      gld16(sAl + dS1, l1);
      gld16(sBl + dS0, qBl0 + k0);
      gld16(sBl + dS1, qBl1 + k0);
    }
    __syncthreads();                      // drains vmcnt -> tile visible

    short8 ah[4], bh[4], al[4], bl[4];
    #pragma unroll
    for (int m = 0; m < 4; m++){
      int off = lds_off(wr + m * 16 + fr, kb);
      ah[m] = *(const short8*)(sAh + off);
      if (SPLIT) al[m] = *(const short8*)(sAl + off);
    }
    #pragma unroll
    for (int n = 0; n < 4; n++){
      int off = lds_off(wc + n * 16 + fr, kb);
      bh[n] = *(const short8*)(sBh + off);
      if (SPLIT) bl[n] = *(const short8*)(sBl + off);
    }
    #pragma unroll
    for (int m = 0; m < 4; m++)
      #pragma unroll
      for (int n = 0; n < 4; n++){
        acc[m][n] = __builtin_amdgcn_mfma_f32_16x16x32_bf16(ah[m], bh[n], acc[m][n], 0, 0, 0);
        if (SPLIT){
          acc[m][n] = __builtin_amdgcn_mfma_f32_16x16x32_bf16(ah[m], bl[n], acc[m][n], 0, 0, 0);
          acc[m][n] = __builtin_amdgcn_mfma_f32_16x16x32_bf16(al[m], bh[n], acc[m][n], 0, 0, 0);
        }
      }
  }

  // epilogue: C/D layout col = lane&15, row = (lane>>4)*4 + reg  [m89-verified]
  const int rbase = (lane >> 4) * 2 * 2;
  const int cbase = lane & 15;
  #pragma unroll
  for (int m = 0; m < 4; m++){
    #pragma unroll
    for (int n = 0; n < 4; n++){
      f32x4 v = acc[m][n];
      int col = n0 + wc + n * 16 + cbase;
      #pragma unroll
      for (int j = 0; j < 4; j++){
        int row = m0 + wr + m * 16 + rbase + j;
        float val = v[j];
        size_t idx = (size_t)row * ldo + col;
        if (EPI == 0){
          unsigned short h = f2bf(val);
          o1[(size_t)z * oStride + idx] = h;
          o2[(size_t)z * oStride + idx] = f2bf(val - bf2f(h));
        } else if (EPI == 1){
          outF[(size_t)z * oStride + idx] = val;
        } else if (EPI == 4){
          o1[(size_t)z * oStride + idx] = f2bf(val);
        } else {
          outF[idx] = tanhf(val);
        }
      }
    }
  }
}

// ---------------------------------------------------------------------------
// GEMM4 kernel (best of 3 structures, R12/R14: ~47 us / 732 TF): 128x128
// counted-vmcnt pipe, 4 waves of 64x64, pure bf16, A split at KSPLIT.
// 48KB LDS -> 3 blocks/CU; triple-buffered; vmcnt(4) per step.
// ---------------------------------------------------------------------------
template<int EPI, int NT, int KSPLIT>
__global__ __launch_bounds__(256, 2) void gemm_pipe128_kernel(
    const unsigned short* __restrict__ Ah, const unsigned short* __restrict__ Ah2,
    const unsigned short* __restrict__ Bh,
    int lda, int ldb,
    float* __restrict__ outF, unsigned short* __restrict__ o1, int ldo)
{
  constexpr int TA  = 8192;               // 128 rows x 64 B
  constexpr int OFF_B = TA;
  constexpr int BUF = 2 * TA;             // 16 KB

  __shared__ __align__(16) char sm0[BUF];
  __shared__ __align__(16) char sm1[BUF];
  __shared__ __align__(16) char sm2[BUF];

  const int tid  = threadIdx.x;
  const int lane = tid & 63;
  const int w    = tid >> 6;              // 0..3

  int bx = blockIdx.x, by = blockIdx.y;
  { // XCD swizzle (grid (8,64))
    int o = bx + (by << 3);
    int xcd = o & 7, j = o >> 3;
    bx = j & 7;
    by = xcd * (gridDim.y >> 3) + (j >> 3);
  }
  const int m0 = by << 7;
  const int n0 = bx << 7;

  const unsigned short* gAh  = Ah  + (size_t)m0 * lda;
  const unsigned short* gAh2 = Ah2 + (size_t)m0 * lda;
  const unsigned short* gBh  = Bh  + (size_t)n0 * ldb;

  const int rS0 = (w << 5) + (lane >> 2);
  const int rS1 = rS0 + 16;
  const int cS0 = ((lane & 3) ^ ((rS0 >> 1) & 3)) << 3;
  const int cS1 = ((lane & 3) ^ ((rS1 >> 1) & 3)) << 3;
  const unsigned short* pA0  = gAh  + (size_t)rS0 * lda + cS0;
  const unsigned short* pA1  = gAh  + (size_t)rS1 * lda + cS1;
  const unsigned short* pA20 = gAh2 + (size_t)rS0 * lda + cS0;
  const unsigned short* pA21 = gAh2 + (size_t)rS1 * lda + cS1;
  const unsigned short* pB0  = gBh  + (size_t)rS0 * ldb + cS0;
  const unsigned short* pB1  = gBh  + (size_t)rS1 * ldb + cS1;
  const int dS0 = (w << 5) << 6;
  const int dS1 = dS0 + (16 << 6);

  f32x4 acc[4][4];
  #pragma unroll
  for (int m = 0; m < 4; m++)
    #pragma unroll
    for (int n = 0; n < 4; n++)
      acc[m][n] = (f32x4){0.f, 0.f, 0.f, 0.f};

  const int wr = (w >> 1) << 6;
  const int wc = (w & 1) << 6;
  const int fr = lane & 15;
  const int kb = lane >> 4;

  short8 ah, bh[4];

#define STAGE(WR, KS) do { int _k = (KS);                                   \
    const unsigned short *_s0, *_s1;                                        \
    if (_k >= KSPLIT){ int _q = _k - KSPLIT; _s0 = pA20 + _q; _s1 = pA21 + _q; } \
    else             { _s0 = pA0 + _k;       _s1 = pA1 + _k; }              \
    gld16(WR + dS0, _s0);                                                   \
    gld16(WR + dS1, _s1);                                                   \
    gld16(WR + OFF_B + dS0, pB0 + _k);                                      \
    gld16(WR + OFF_B + dS1, pB1 + _k);                                      \
  } while(0)

#define READS_B(RD) do {                                                    \
    _Pragma("unroll")                                                       \
    for (int n = 0; n < 4; n++)                                             \
      bh[n] = *(const short8*)((RD) + OFF_B + lds_off(wc + n * 16 + fr, kb)); \
  } while(0)

#define READS_A(RD, M)                                                      \
    ah = *(const short8*)((RD) + lds_off(wr + (M) * 16 + fr, kb))

#define MFMA_M(M) do {                                                      \
    __builtin_amdgcn_s_setprio(1);                                          \
    _Pragma("unroll")                                                       \
    for (int n = 0; n < 4; n++)                                             \
      acc[M][n] = __builtin_amdgcn_mfma_f32_16x16x32_bf16(ah, bh[n], acc[M][n], 0, 0, 0); \
    __builtin_amdgcn_s_setprio(0);                                          \
  } while(0)

#define BAR() do { __builtin_amdgcn_s_barrier();                            \
                   asm volatile("" ::: "memory"); } while(0)
#define LGKM0() asm volatile("s_waitcnt lgkmcnt(0)" ::: "memory")
#define VMCNT4() asm volatile("s_waitcnt vmcnt(4)" ::: "memory")

#define STEP(RD, WR, T) do {                                                \
    int _ks = (((T) + 2 < NT) ? (T) + 2 : NT - 1) << 5;  /* dead-stage clamp */ \
    READS_B(RD); READS_A(RD, 0);                                            \
    STAGE(WR, _ks);                                                         \
    BAR(); LGKM0(); MFMA_M(0); BAR();                                       \
    READS_A(RD, 1);                                                        \
    BAR(); LGKM0(); MFMA_M(1); BAR();                                       \
    READS_A(RD, 2);                                                        \
    BAR(); LGKM0(); MFMA_M(2); BAR();                                       \
    READS_A(RD, 3);                                                        \
    BAR(); LGKM0(); MFMA_M(3);                                              \
    VMCNT4();                                                               \
    BAR();                                                                  \
  } while(0)

  STAGE(sm0, 0);
  STAGE(sm1, 32);
  VMCNT4();       // retires tile 0's 4 loads
  BAR();

  for (int t = 0; t < NT; t += 3){
    STEP(sm0, sm2, t);
    if (t + 1 < NT) STEP(sm1, sm0, t + 1);
    if (t + 2 < NT) STEP(sm2, sm1, t + 2);
  }
#undef STAGE
#undef READS_B
#undef READS_A
#undef MFMA_M
#undef BAR
#undef LGKM0
#undef VMCNT4
#undef STEP

  // epilogue: C/D layout col = lane&15, row = (lane>>4)*4 + reg  [m89-verified]
  const int rbase = (lane >> 4) << 2;
  const int cbase = lane & 15;
  #pragma unroll
  for (int m = 0; m < 4; m++){
    #pragma unroll
    for (int n = 0; n < 4; n++){
      f32x4 v = acc[m][n];
      int col = n0 + wc + n * 16 + cbase;
      #pragma unroll
      for (int j = 0; j < 4; j++){
        int row = m0 + wr + m * 16 + rbase + j;
        float val = v[j];
        size_t idx = (size_t)row * ldo + col;
        if (EPI == 3) outF[idx] = tanhf(val);
        else          o1[idx] = f2bf(val);
      }
    }
  }
}

extern "C" void kernel_launch(void* const* d_in, const int* in_sizes, int n_in,
                              void* d_out, int out_size, void* d_ws, size_t ws_size,
                              hipStream_t stream){
  const float* input   = (const float*)d_in[0];
  const float* context = (const float*)d_in[1];
  const int*   lens    = (const int*)d_in[2];
  const float* Win     = (const float*)d_in[3];
  const float* Wout    = (const float*)d_in[4];
  float* attn  = (float*)d_out;
  float* align = attn + (size_t)BT * DIM;

  char* ws = (char*)d_ws;
  size_t off = 0;
  auto alloc = [&](size_t bytes) -> char* {
    char* p = ws + off; off += (bytes + 255) & ~(size_t)255; return p;
  };
  const size_t MTD = (size_t)BT * DIM;   // 8M elements
  unsigned short* in_hi = (unsigned short*)alloc(MTD * 2);
  unsigned short* in_lo = (unsigned short*)alloc(MTD * 2);
  unsigned short* cx_hi = (unsigned short*)alloc(MTD * 2);
  unsigned short* cx_lo = (unsigned short*)alloc(MTD * 2);
  unsigned short* wi_hi = (unsigned short*)alloc((size_t)DIM * DIM * 2);
  unsigned short* wi_lo = (unsigned short*)alloc((size_t)DIM * DIM * 2);
  unsigned short* ht_hi = (unsigned short*)alloc(MTD * 2);
  unsigned short* ht_lo = (unsigned short*)alloc(MTD * 2);
  unsigned short* cxT   = (unsigned short*)alloc(MTD * 2);
  unsigned short* c_hi  = (unsigned short*)alloc(MTD * 2);   // GEMM3 out (plain bf16)
  unsigned short* wo_hi = (unsigned short*)alloc((size_t)DIM * 2 * DIM * 2);
  unsigned short* p_bf  = cx_hi;   // alias: cx_hi dead after GEMM2
  if (off > ws_size) return;

  // prep: merged elementwise + fused vectorized context split/transpose
  prep_kernel<<<4096, 256, 0, stream>>>(input, in_hi, in_lo,
                                        Win, wi_hi, wi_lo, Wout, wo_hi);
  ctx_prep_kernel<<<dim3(16, 16, NBAT), 256, 0, stream>>>(context, cx_hi, cx_lo, cxT);

  // GEMM1: ht = input @ Win^T  (2-barrier 128^2 SPLIT, 930 TF measured R14)
  gemm_kernel<true, 0, KSOFF><<<dim3(8, 64, 1), 256, 0, stream>>>(
      in_hi, in_lo, in_hi, in_lo, wi_hi, wi_lo, DIM, DIM, DIM,
      0, 0, 0,
      nullptr, ht_hi, ht_lo, DIM, nullptr, 0);
  // GEMM2: scores[b] = ht[b] @ ctx[b]^T  (SPLIT, f32 out -> align; len-skip)
  gemm_kernel<true, 1, KSOFF><<<dim3(8, 8, NBAT), 256, 0, stream>>>(
      ht_hi, ht_lo, ht_hi, ht_lo, cx_hi, cx_lo, DIM, DIM, DIM,
      (long long)DIM * 1024, (long long)DIM * 1024, (long long)DIM * 1024,
      align, nullptr, nullptr, DIM, lens, 1);
  // masked softmax (in-place on align) + P bf16
  softmax_kernel<<<BT, 256, 0, stream>>>(align, p_bf, lens);
  // GEMM3: c[b] = P[b] @ ctxT[b]^T  (plain bf16, len-clamped K)
  gemm_kernel<false, 4, KSOFF><<<dim3(8, 8, NBAT), 256, 0, stream>>>(
      p_bf, nullptr, p_bf, nullptr, cxT, nullptr, DIM, DIM, DIM,
      (long long)DIM * 1024, (long long)DIM * 1024, (long long)1024 * 1024,
      nullptr, c_hi, nullptr, DIM, lens, 2);
  // GEMM4: attn = tanh([c | input] @ Wout^T)  (counted-vmcnt 128^2 pipe,
  //        best of three structures tried: 732 TF)
  gemm_pipe128_kernel<3, 64, 1024><<<dim3(8, 64), 256, 0, stream>>>(
      c_hi, in_hi, wo_hi, DIM, 2 * DIM,
      attn, nullptr, DIM);
}